// Round 2
// 436.859 us; speedup vs baseline: 1.3543x; 1.3543x over previous
//
#include <hip/hip_runtime.h>
#include <hip/hip_bf16.h>

#define SS 2048
#define DDIM 1024

typedef unsigned short u16;
typedef unsigned int u32;
typedef __attribute__((ext_vector_type(8))) short bf16x8_t;
typedef __attribute__((ext_vector_type(4))) float f32x4_t;

__device__ __forceinline__ u16 f2bf(float f) {
  __hip_bfloat16 h = __float2bfloat16(f);
  return *reinterpret_cast<u16*>(&h);
}

// async global->LDS, 16 B per lane. LDS dest = (wave-uniform) base + lane*16.
__device__ __forceinline__ void gld16(const void* g, void* lds_base) {
  __builtin_amdgcn_global_load_lds(
      (const __attribute__((address_space(1))) u32*)(uintptr_t)g,
      (__attribute__((address_space(3))) u32*)(u32)(uintptr_t)lds_base,
      16, 0, 0);
}

// ---------------------------------------------------------------------------
__global__ void zero_kernel(u32* zb) { zb[threadIdx.x] = 0u; }

// f32 -> bf16 flat convert, 8 elems/thread; blockIdx.y selects q/k/v.
__global__ __launch_bounds__(256) void convert3_kernel(
    const float* __restrict__ q, const float* __restrict__ k,
    const float* __restrict__ v, u16* __restrict__ Xq, u16* __restrict__ Xk,
    u16* __restrict__ Xv) {
  const int z = blockIdx.y;
  const float* src = (z == 0) ? q : (z == 1) ? k : v;
  u16* dst = (z == 0) ? Xq : (z == 1) ? Xk : Xv;
  int i = blockIdx.x * 256 + threadIdx.x;
  const float4* s = (const float4*)src + (size_t)i * 2;
  float4 f0 = s[0], f1 = s[1];
  u16 o[8] = {f2bf(f0.x), f2bf(f0.y), f2bf(f0.z), f2bf(f0.w),
              f2bf(f1.x), f2bf(f1.y), f2bf(f1.z), f2bf(f1.w)};
  *(uint4*)(dst + (size_t)i * 8) = *(const uint4*)o;
}

// conv3 weight w[o][i][t] f32 -> Wr[o][t*1024+i] bf16; blockIdx.y: wq/wk.
__global__ __launch_bounds__(256) void repack3_kernel(
    const float* __restrict__ wq, const float* __restrict__ wk,
    u16* __restrict__ Wqr, u16* __restrict__ Wkr) {
  const float* w = blockIdx.y ? wk : wq;
  u16* out = blockIdx.y ? Wkr : Wqr;
  int o = blockIdx.x;
  for (int j = threadIdx.x; j < 3072; j += 256) {
    int i = j / 3, t = j - i * 3;
    out[(size_t)o * 3072 + t * 1024 + i] = f2bf(w[(size_t)o * 3072 + j]);
  }
}

// square weight [o][k] f32 -> bf16; blockIdx.y: wv/wc.
__global__ __launch_bounds__(256) void repackc_kernel(
    const float* __restrict__ wv, const float* __restrict__ wc,
    u16* __restrict__ Wvr, u16* __restrict__ Wcr) {
  const float* w = blockIdx.y ? wc : wv;
  u16* out = blockIdx.y ? Wcr : Wvr;
  size_t i = (size_t)blockIdx.x * 1024 + threadIdx.x * 4;
  float4 f = *(const float4*)(w + i);
  u16 o4[4] = {f2bf(f.x), f2bf(f.y), f2bf(f.z), f2bf(f.w)};
  *(ushort4*)(out + i) = *(const ushort4*)o4;
}

// ---------------------------------------------------------------------------
// Merged Q/K/V projection GEMM. grid (32, 8, 3): z selects the GEMM.
// z=0: Qhb = conv(Xq,Wq)+bq, head layout, scale 0.125
// z=1: Khb = conv(Xk,Wk)+bk, head layout
// z=2: Vtb = Xv*Wv+bv, V-transposed layout
// 768 blocks -> ~3 blocks/CU co-resident: the vmcnt(0)+barrier drain of one
// block hides under another block's MFMA (the 1-block/CU launch couldn't).
// Same 128x128 tile / BK=32 / 4-wave structure as before.
// ---------------------------------------------------------------------------
__global__ __launch_bounds__(256) void mfma_proj(
    const u16* __restrict__ Xq, const u16* __restrict__ Xk,
    const u16* __restrict__ Xv, const u16* __restrict__ Wq,
    const u16* __restrict__ Wk, const u16* __restrict__ Wv,
    const float* __restrict__ bq, const float* __restrict__ bk,
    const float* __restrict__ bv, u16* __restrict__ Qhb,
    u16* __restrict__ Khb, u16* __restrict__ Vtb,
    const u16* __restrict__ zbuf) {
  __shared__ __attribute__((aligned(16))) u16 As[128][40];
  __shared__ __attribute__((aligned(16))) u16 Bs[128][40];
  const int z = blockIdx.z;
  const u16* __restrict__ Xb = (z == 0) ? Xq : (z == 1) ? Xk : Xv;
  const u16* __restrict__ Wr = (z == 0) ? Wq : (z == 1) ? Wk : Wv;
  const float* __restrict__ bias = (z == 0) ? bq : (z == 1) ? bk : bv;
  u16* __restrict__ Cptr = (z == 0) ? Qhb : (z == 1) ? Khb : Vtb;
  const int Kdim = (z == 2) ? 1024 : 3072;
  const bool conv = (z < 2);
  const bool vout = (z == 2);
  const float scale = (z == 0) ? 0.125f : 1.0f;

  const int tid = threadIdx.x;
  const int lane = tid & 63;
  const int w = tid >> 6;
  const int ln = tid & 15;
  const int quad = (tid >> 4) & 3;
  const int wrow = w >> 1, wcol = w & 1;
  const int m0 = blockIdx.x * 128, n0 = blockIdx.y * 128;

  f32x4_t acc[4][4];
#pragma unroll
  for (int i = 0; i < 4; ++i)
#pragma unroll
    for (int j = 0; j < 4; ++j) acc[i][j] = (f32x4_t){0.f, 0.f, 0.f, 0.f};

  for (int k0 = 0; k0 < Kdim; k0 += 32) {
    __syncthreads();
    for (int c = w; c < 10; c += 4) {
      int G = c * 64 + lane;
      int x = G / 5, kb = G - x * 5;
      if (kb < 4) {
        int gm = m0 + x;
        const u16* src;
        if (conv) {
          int b = gm >> 11, s = gm & 2047;
          int t = k0 >> 10;
          int sp = s + t - 1;
          src = (sp >= 0 && sp < SS)
                    ? Xb + ((size_t)(b * SS + sp) * DDIM + (k0 & 1023) + kb * 8)
                    : zbuf;
        } else {
          src = Xb + ((size_t)gm * DDIM + k0 + kb * 8);
        }
        gld16(src, (char*)As + c * 1024);
      }
    }
    for (int c = w; c < 10; c += 4) {
      int G = c * 64 + lane;
      int x = G / 5, kb = G - x * 5;
      if (kb < 4) {
        const u16* src = Wr + (size_t)(n0 + x) * Kdim + k0 + kb * 8;
        gld16(src, (char*)Bs + c * 1024);
      }
    }
    __syncthreads();

    bf16x8_t a[4], b[4];
#pragma unroll
    for (int mt = 0; mt < 4; ++mt)
      a[mt] = *(const bf16x8_t*)&As[wrow * 64 + mt * 16 + ln][quad * 8];
#pragma unroll
    for (int nt = 0; nt < 4; ++nt)
      b[nt] = *(const bf16x8_t*)&Bs[wcol * 64 + nt * 16 + ln][quad * 8];
#pragma unroll
    for (int mt = 0; mt < 4; ++mt)
#pragma unroll
      for (int nt = 0; nt < 4; ++nt)
        acc[mt][nt] = __builtin_amdgcn_mfma_f32_16x16x32_bf16(
            a[mt], b[nt], acc[mt][nt], 0, 0, 0);
  }

#pragma unroll
  for (int mt = 0; mt < 4; ++mt) {
#pragma unroll
    for (int nt = 0; nt < 4; ++nt) {
      int gn = n0 + wcol * 64 + nt * 16 + ln;
      float bi = bias[gn];
#pragma unroll
      for (int r = 0; r < 4; ++r) {
        int gm = m0 + wrow * 64 + mt * 16 + quad * 4 + r;
        float val = (acc[mt][nt][r] + bi) * scale;
        int b = gm >> 11, s = gm & 2047;
        int hh = gn & 15, dd = gn >> 4;  // channel = dd*16 + hh (head FAST)
        if (!vout)
          Cptr[((size_t)(b * 16 + hh) * SS + s) * 64 + dd] = f2bf(val);
        else
          Cptr[((size_t)(b * 16 + hh) * 64 + dd) * SS + s] = f2bf(val);
      }
    }
  }
}

// ---------------------------------------------------------------------------
// Final linear GEMM: C[M=4096][N=1024] f32 = Aob[M][K=1024] * Wcr[n][k] + b.
// Same 128x128/BK=32 structure (single instance of the old template).
// ---------------------------------------------------------------------------
__global__ __launch_bounds__(256) void mfma_gemm_lin(
    const u16* __restrict__ Xb, const u16* __restrict__ Wr,
    const float* __restrict__ bias, float* __restrict__ Cptr) {
  __shared__ __attribute__((aligned(16))) u16 As[128][40];
  __shared__ __attribute__((aligned(16))) u16 Bs[128][40];
  const int tid = threadIdx.x;
  const int lane = tid & 63;
  const int w = tid >> 6;
  const int ln = tid & 15;
  const int quad = (tid >> 4) & 3;
  const int wrow = w >> 1, wcol = w & 1;
  const int m0 = blockIdx.x * 128, n0 = blockIdx.y * 128;

  f32x4_t acc[4][4];
#pragma unroll
  for (int i = 0; i < 4; ++i)
#pragma unroll
    for (int j = 0; j < 4; ++j) acc[i][j] = (f32x4_t){0.f, 0.f, 0.f, 0.f};

  for (int k0 = 0; k0 < 1024; k0 += 32) {
    __syncthreads();
    for (int c = w; c < 10; c += 4) {
      int G = c * 64 + lane;
      int x = G / 5, kb = G - x * 5;
      if (kb < 4)
        gld16(Xb + ((size_t)(m0 + x) * DDIM + k0 + kb * 8), (char*)As + c * 1024);
    }
    for (int c = w; c < 10; c += 4) {
      int G = c * 64 + lane;
      int x = G / 5, kb = G - x * 5;
      if (kb < 4)
        gld16(Wr + (size_t)(n0 + x) * 1024 + k0 + kb * 8, (char*)Bs + c * 1024);
    }
    __syncthreads();

    bf16x8_t a[4], b[4];
#pragma unroll
    for (int mt = 0; mt < 4; ++mt)
      a[mt] = *(const bf16x8_t*)&As[wrow * 64 + mt * 16 + ln][quad * 8];
#pragma unroll
    for (int nt = 0; nt < 4; ++nt)
      b[nt] = *(const bf16x8_t*)&Bs[wcol * 64 + nt * 16 + ln][quad * 8];
#pragma unroll
    for (int mt = 0; mt < 4; ++mt)
#pragma unroll
      for (int nt = 0; nt < 4; ++nt)
        acc[mt][nt] = __builtin_amdgcn_mfma_f32_16x16x32_bf16(
            a[mt], b[nt], acc[mt][nt], 0, 0, 0);
  }

#pragma unroll
  for (int mt = 0; mt < 4; ++mt) {
#pragma unroll
    for (int nt = 0; nt < 4; ++nt) {
      int gn = n0 + wcol * 64 + nt * 16 + ln;
      float bi = bias[gn];
#pragma unroll
      for (int r = 0; r < 4; ++r) {
        int gm = m0 + wrow * 64 + mt * 16 + quad * 4 + r;
        Cptr[(size_t)gm * DDIM + gn] = acc[mt][nt][r] + bi;
      }
    }
  }
}

// ---------------------------------------------------------------------------
// MFMA flash attention. Changes vs round 0:
//  - row-sum reduce moved OUT of the K loop (lane-partial lsum, reduced once
//    in the epilogue): removes 16 shfl_xor + 16 adds per K-tile.
//  - wave-uniform deferred rescale: if no row's max grew (__any), skip the
//    al-exp + 20 rescale muls. Skip only when mx<=mrow -> P<=1, exact.
// ---------------------------------------------------------------------------
__global__ __launch_bounds__(256) void mfma_attn(
    const u16* __restrict__ Qhb, const u16* __restrict__ Khb,
    const u16* __restrict__ Vtb, u16* __restrict__ Aob,
    const u16* __restrict__ zbuf) {
  __shared__ __attribute__((aligned(16))) u16 Ks[64][72];
  __shared__ __attribute__((aligned(16))) u16 Vt[64][72];
  __shared__ __attribute__((aligned(16))) u16 Ps[4][16][72];
  const int tid = threadIdx.x;
  const int lane = tid & 63;
  const int w = tid >> 6;
  const int ln = tid & 15;
  const int quad = (tid >> 4) & 3;
  const int bh = blockIdx.y;
  const int b = bh >> 4, hh = bh & 15;
  const int s0 = blockIdx.x * 64;

  const u16* qp = Qhb + ((size_t)bh * SS + s0 + w * 16 + ln) * 64 + quad * 8;
  bf16x8_t qf0 = *(const bf16x8_t*)qp;
  bf16x8_t qf1 = *(const bf16x8_t*)(qp + 32);

  float mrow[4], lsum[4];
  f32x4_t oacc[4];
#pragma unroll
  for (int r = 0; r < 4; ++r) { mrow[r] = -3e38f; lsum[r] = 0.f; }
#pragma unroll
  for (int dt = 0; dt < 4; ++dt) oacc[dt] = (f32x4_t){0.f, 0.f, 0.f, 0.f};

  for (int kt = 0; kt < 32; ++kt) {
    __syncthreads();
    for (int c = w; c < 9; c += 4) {
      int G = c * 64 + lane;
      int x = G / 9, db = G - x * 9;
      if (db < 8) {
        gld16(Khb + ((size_t)bh * SS + kt * 64 + x) * 64 + db * 8,
              (char*)Ks + c * 1024);
        gld16(Vtb + ((size_t)bh * 64 + x) * SS + kt * 64 + db * 8,
              (char*)Vt + c * 1024);
      }
    }
    __syncthreads();

    f32x4_t sc[4];
#pragma unroll
    for (int nt = 0; nt < 4; ++nt) sc[nt] = (f32x4_t){0.f, 0.f, 0.f, 0.f};
#pragma unroll
    for (int nt = 0; nt < 4; ++nt) {
      bf16x8_t k0f = *(const bf16x8_t*)&Ks[nt * 16 + ln][quad * 8];
      sc[nt] = __builtin_amdgcn_mfma_f32_16x16x32_bf16(qf0, k0f, sc[nt], 0, 0, 0);
      bf16x8_t k1f = *(const bf16x8_t*)&Ks[nt * 16 + ln][32 + quad * 8];
      sc[nt] = __builtin_amdgcn_mfma_f32_16x16x32_bf16(qf1, k1f, sc[nt], 0, 0, 0);
    }

    // row max reduce (quad group); wave-uniform deferred rescale
    float mxv[4];
    bool need = false;
#pragma unroll
    for (int r = 0; r < 4; ++r) {
      float mx = fmaxf(fmaxf(sc[0][r], sc[1][r]), fmaxf(sc[2][r], sc[3][r]));
      mx = fmaxf(mx, __shfl_xor(mx, 1, 64));
      mx = fmaxf(mx, __shfl_xor(mx, 2, 64));
      mx = fmaxf(mx, __shfl_xor(mx, 4, 64));
      mx = fmaxf(mx, __shfl_xor(mx, 8, 64));
      mxv[r] = mx;
      need = need || (mx > mrow[r]);
    }
    if (__any(need)) {
#pragma unroll
      for (int r = 0; r < 4; ++r) {
        float mn = fmaxf(mrow[r], mxv[r]);
        float al = __expf(mrow[r] - mn);
        mrow[r] = mn;
        lsum[r] *= al;
#pragma unroll
        for (int dt = 0; dt < 4; ++dt) oacc[dt][r] *= al;
      }
    }
#pragma unroll
    for (int r = 0; r < 4; ++r) {
      float p0 = __expf(sc[0][r] - mrow[r]), p1 = __expf(sc[1][r] - mrow[r]);
      float p2 = __expf(sc[2][r] - mrow[r]), p3 = __expf(sc[3][r] - mrow[r]);
      lsum[r] += p0 + p1 + p2 + p3;
      Ps[w][quad * 4 + r][ln] = f2bf(p0);
      Ps[w][quad * 4 + r][16 + ln] = f2bf(p1);
      Ps[w][quad * 4 + r][32 + ln] = f2bf(p2);
      Ps[w][quad * 4 + r][48 + ln] = f2bf(p3);
    }

    // PV (P read back in A-operand layout; same-wave LDS program order)
    bf16x8_t pa0 = *(const bf16x8_t*)&Ps[w][ln][quad * 8];
    bf16x8_t pa1 = *(const bf16x8_t*)&Ps[w][ln][32 + quad * 8];
#pragma unroll
    for (int dt = 0; dt < 4; ++dt) {
      bf16x8_t v0f = *(const bf16x8_t*)&Vt[dt * 16 + ln][quad * 8];
      oacc[dt] = __builtin_amdgcn_mfma_f32_16x16x32_bf16(pa0, v0f, oacc[dt], 0, 0, 0);
      bf16x8_t v1f = *(const bf16x8_t*)&Vt[dt * 16 + ln][32 + quad * 8];
      oacc[dt] = __builtin_amdgcn_mfma_f32_16x16x32_bf16(pa1, v1f, oacc[dt], 0, 0, 0);
    }
  }

  // epilogue: reduce lane-partial sums once, normalize, store
  float inv[4];
#pragma unroll
  for (int r = 0; r < 4; ++r) {
    float t = lsum[r];
    t += __shfl_xor(t, 1, 64);
    t += __shfl_xor(t, 2, 64);
    t += __shfl_xor(t, 4, 64);
    t += __shfl_xor(t, 8, 64);
    inv[r] = 1.f / t;
  }
#pragma unroll
  for (int dt = 0; dt < 4; ++dt)
#pragma unroll
    for (int r = 0; r < 4; ++r) {
      int gm = b * SS + s0 + w * 16 + quad * 4 + r;
      Aob[(size_t)gm * DDIM + hh * 64 + dt * 16 + ln] = f2bf(oacc[dt][r] * inv[r]);
    }
}

// ---------------------------------------------------------------------------
// Launch
// ---------------------------------------------------------------------------
extern "C" void kernel_launch(void* const* d_in, const int* in_sizes, int n_in,
                              void* d_out, int out_size, void* d_ws, size_t ws_size,
                              hipStream_t stream) {
  const float* q    = (const float*)d_in[0];
  const float* k    = (const float*)d_in[1];
  const float* v    = (const float*)d_in[2];
  const float* wq_w = (const float*)d_in[3];
  const float* wq_b = (const float*)d_in[4];
  const float* wk_w = (const float*)d_in[5];
  const float* wk_b = (const float*)d_in[6];
  const float* wv_w = (const float*)d_in[7];
  const float* wv_b = (const float*)d_in[8];
  const float* wc_w = (const float*)d_in[9];
  const float* wc_b = (const float*)d_in[10];

  char* ws = (char*)d_ws;
  size_t off = 0;
  u16* zbuf = (u16*)(ws + off); off += 256;
  const size_t SZ_ACT = (size_t)2 * SS * DDIM * 2;  // 8 MB bf16
  u16* Xq  = (u16*)(ws + off); off += SZ_ACT;
  u16* Xk  = (u16*)(ws + off); off += SZ_ACT;
  u16* Xv  = (u16*)(ws + off); off += SZ_ACT;
  u16* Wqr = (u16*)(ws + off); off += (size_t)1024 * 3072 * 2;
  u16* Wkr = (u16*)(ws + off); off += (size_t)1024 * 3072 * 2;
  u16* Wvr = (u16*)(ws + off); off += (size_t)1024 * 1024 * 2;
  u16* Wcr = (u16*)(ws + off); off += (size_t)1024 * 1024 * 2;
  u16* Qhb = (u16*)(ws + off); off += SZ_ACT;
  u16* Khb = (u16*)(ws + off); off += SZ_ACT;
  u16* Vtb = (u16*)(ws + off); off += SZ_ACT;
  u16* Aob = (u16*)(ws + off); off += SZ_ACT;
  if (ws_size < off) return;

  zero_kernel<<<1, 64, 0, stream>>>((u32*)zbuf);
  convert3_kernel<<<dim3(2048, 3), 256, 0, stream>>>(q, k, v, Xq, Xk, Xv);
  repack3_kernel<<<dim3(1024, 2), 256, 0, stream>>>(wq_w, wk_w, Wqr, Wkr);
  repackc_kernel<<<dim3(1024, 2), 256, 0, stream>>>(wv_w, wc_w, Wvr, Wcr);

  // merged Q/K/V projections: 768 blocks -> ~3 blocks/CU
  mfma_proj<<<dim3(32, 8, 3), 256, 0, stream>>>(
      Xq, Xk, Xv, Wqr, Wkr, Wvr, wq_b, wk_b, wv_b, Qhb, Khb, Vtb, zbuf);

  mfma_attn<<<dim3(32, 32), 256, 0, stream>>>(Qhb, Khb, Vtb, Aob, zbuf);

  mfma_gemm_lin<<<dim3(32, 8), 256, 0, stream>>>(Aob, Wcr, wc_b, (float*)d_out);
}